// Round 6
// baseline (437.503 us; speedup 1.0000x reference)
//
#include <hip/hip_runtime.h>

#define NN 50000
#define NE 800000
#define F 128
#define NREL 4
#define RN (NREL * NN)          // number of segments
#define NB 196                  // scan blocks: ceil(RN / 1024)
#define BN_EPS 1e-5f
#define ROWS 64                 // rows per block tile
#define LDW 136                 // padded LDS row stride in bf16 elems

typedef __attribute__((ext_vector_type(8))) short short8;
typedef __attribute__((ext_vector_type(4))) float floatx4;

__device__ __forceinline__ ushort f2bf(float f) {
    union { float f; unsigned u; } v; v.f = f;
    unsigned r = v.u + 0x7fffu + ((v.u >> 16) & 1u);
    return (ushort)(r >> 16);
}
__device__ __forceinline__ float ubf(unsigned bits) {
    union { unsigned u; float f; } v; v.u = bits; return v.f;
}
__device__ __forceinline__ unsigned pk2(float a, float b) {
    return (unsigned)f2bf(a) | ((unsigned)f2bf(b) << 16);
}
__device__ __forceinline__ void acc_u4(float* acc, uint4 v) {
    acc[0] += ubf(v.x << 16); acc[1] += ubf(v.x & 0xffff0000u);
    acc[2] += ubf(v.y << 16); acc[3] += ubf(v.y & 0xffff0000u);
    acc[4] += ubf(v.z << 16); acc[5] += ubf(v.z & 0xffff0000u);
    acc[6] += ubf(v.w << 16); acc[7] += ubf(v.w & 0xffff0000u);
}

// ---------------- xb = bf16(x) ----------------
__global__ __launch_bounds__(256) void xb_kernel(
    const float* __restrict__ x, ushort* __restrict__ xb)
{
    int i = blockIdx.x * 256 + threadIdx.x;   // handles 4 floats; NN*F/4 threads exactly
    float4 v = *(const float4*)(x + (size_t)i * 4);
    uint2 u;
    u.x = pk2(v.x, v.y);
    u.y = pk2(v.z, v.w);
    *(uint2*)(xb + (size_t)i * 4) = u;
}

// ---------------- histogram: counts[rel*NN+dst]++ ----------------
__global__ __launch_bounds__(256) void hist_kernel(
    const int* __restrict__ ei, const int* __restrict__ et, int* __restrict__ counts)
{
    int e = blockIdx.x * 256 + threadIdx.x;
    if (e >= NE) return;
    atomicAdd(&counts[et[e] * NN + ei[NE + e]], 1);
}

// ---------------- scan stage 1 ----------------
__global__ __launch_bounds__(256) void scan1_kernel(
    const int* __restrict__ counts, int* __restrict__ rowptr, int* __restrict__ bsum)
{
    __shared__ int wsum[4];
    const int tid = threadIdx.x;
    const int base = blockIdx.x * 1024 + tid * 4;
    int c[4];
    #pragma unroll
    for (int j = 0; j < 4; j++) c[j] = (base + j < RN) ? counts[base + j] : 0;
    int tsum = c[0] + c[1] + c[2] + c[3];
    const int lane = tid & 63, wv = tid >> 6;
    int s = tsum;
    #pragma unroll
    for (int d = 1; d < 64; d <<= 1) { int t = __shfl_up(s, d); if (lane >= d) s += t; }
    if (lane == 63) wsum[wv] = s;
    __syncthreads();
    int wave_off = 0;
    #pragma unroll
    for (int w = 0; w < 4; w++) if (w < wv) wave_off += wsum[w];
    int run = wave_off + s - tsum;
    #pragma unroll
    for (int j = 0; j < 4; j++) {
        if (base + j < RN) rowptr[base + j] = run;
        run += c[j];
    }
    if (tid == 0) bsum[blockIdx.x] = wsum[0] + wsum[1] + wsum[2] + wsum[3];
}

// ---------------- scan stage 2 ----------------
__global__ __launch_bounds__(256) void scan2_kernel(
    const int* __restrict__ bsum, int* __restrict__ boff, int* __restrict__ rowptr)
{
    __shared__ int wsum[4];
    const int tid = threadIdx.x;
    int v = (tid < NB) ? bsum[tid] : 0;
    const int lane = tid & 63, wv = tid >> 6;
    int s = v;
    #pragma unroll
    for (int d = 1; d < 64; d <<= 1) { int t = __shfl_up(s, d); if (lane >= d) s += t; }
    if (lane == 63) wsum[wv] = s;
    __syncthreads();
    int wave_off = 0;
    #pragma unroll
    for (int w = 0; w < 4; w++) if (w < wv) wave_off += wsum[w];
    if (tid < NB) boff[tid] = wave_off + s - v;
    if (tid == 0) rowptr[RN] = wsum[0] + wsum[1] + wsum[2] + wsum[3];   // == NE
}

// ---------------- scan stage 3 ----------------
__global__ __launch_bounds__(256) void scan3_kernel(
    int* __restrict__ rowptr, const int* __restrict__ boff, int* __restrict__ cursor)
{
    const int base = blockIdx.x * 1024 + threadIdx.x * 4;
    const int off = boff[blockIdx.x];
    #pragma unroll
    for (int j = 0; j < 4; j++) {
        int idx = base + j;
        if (idx < RN) { int v = rowptr[idx] + off; rowptr[idx] = v; cursor[idx] = v; }
    }
}

// ---------------- reorder ----------------
__global__ __launch_bounds__(256) void reorder_kernel(
    const int* __restrict__ ei, const int* __restrict__ et,
    int* __restrict__ cursor, int* __restrict__ sorted_src)
{
    int e = blockIdx.x * 256 + threadIdx.x;
    if (e >= NE) return;
    int key = et[e] * NN + ei[NE + e];
    int pos = atomicAdd(&cursor[key], 1);
    sorted_src[pos] = ei[e];
}

// ------- gather: hbuf[row] = bf16(xb[n] + sum_{e in seg(row)} xb[src_e]) -------
__global__ __launch_bounds__(256) void gather_kernel(
    const ushort* __restrict__ xb, const int* __restrict__ rowptr,
    const int* __restrict__ sorted_src, ushort* __restrict__ hbuf)
{
    const int t = blockIdx.x * 256 + threadIdx.x;
    const int row = t >> 4;               // segment id in [0, RN)
    const int lane = t & 15;              // 16 lanes x 8 bf16 = 128 feats
    const int n = row % NN;               // dst node

    const uint4* xv = (const uint4*)xb;   // row stride = 16 uint4
    float acc[8];
    {
        uint4 v = xv[n * 16 + lane];
        acc[0] = ubf(v.x << 16); acc[1] = ubf(v.x & 0xffff0000u);
        acc[2] = ubf(v.y << 16); acc[3] = ubf(v.y & 0xffff0000u);
        acc[4] = ubf(v.z << 16); acc[5] = ubf(v.z & 0xffff0000u);
        acc[6] = ubf(v.w << 16); acc[7] = ubf(v.w & 0xffff0000u);
    }
    int e = rowptr[row];
    const int e1 = rowptr[row + 1];
    for (; e + 2 <= e1; e += 2) {
        int s0 = sorted_src[e];
        int s1 = sorted_src[e + 1];
        uint4 a = xv[s0 * 16 + lane];
        uint4 b = xv[s1 * 16 + lane];
        acc_u4(acc, a);
        acc_u4(acc, b);
    }
    if (e < e1) {
        int s0 = sorted_src[e];
        acc_u4(acc, xv[s0 * 16 + lane]);
    }
    uint4 o;
    o.x = pk2(acc[0], acc[1]);
    o.y = pk2(acc[2], acc[3]);
    o.z = pk2(acc[4], acc[5]);
    o.w = pk2(acc[6], acc[7]);
    *(uint4*)(hbuf + (size_t)row * F + lane * 8) = o;
}

// ---------------- prep: weights -> bf16 transposed Wt_g[mat][n][k] ----------------
// mats 0..3 = W1[r], 4..7 = W2[r], 8 = Wself
__global__ __launch_bounds__(256) void prep_kernel(
    const float* __restrict__ W1, const float* __restrict__ W2,
    const float* __restrict__ Wself, ushort* __restrict__ Wt_g)
{
    __shared__ ushort Lt[F * F];   // 32 KB
    int m = blockIdx.x;
    const float* src = (m < 4) ? (W1 + (size_t)m * F * F)
                     : (m < 8) ? (W2 + (size_t)(m - 4) * F * F)
                               : Wself;
    int tid = threadIdx.x;
    #pragma unroll
    for (int p = 0; p < 16; p++) {
        int i4 = tid + p * 256;
        int k = i4 >> 5;
        int n4 = (i4 & 31) * 4;
        float4 v = *(const float4*)(src + (size_t)k * F + n4);
        Lt[(n4 + 0) * F + k] = f2bf(v.x);
        Lt[(n4 + 1) * F + k] = f2bf(v.y);
        Lt[(n4 + 2) * F + k] = f2bf(v.z);
        Lt[(n4 + 3) * F + k] = f2bf(v.w);
    }
    __syncthreads();
    #pragma unroll
    for (int p = 0; p < 8; p++) {
        int c = tid + p * 256;
        *(uint4*)(Wt_g + (size_t)m * F * F + c * 8) = *(const uint4*)&Lt[c * 8];
    }
}

// ---------------- bn coefficients + total bias ----------------
__global__ __launch_bounds__(256) void bncoef_kernel(
    const float* __restrict__ sums, const float* __restrict__ sumsq,
    const float* __restrict__ gamma, const float* __restrict__ beta,
    const float* __restrict__ b2, const float* __restrict__ bself,
    float* __restrict__ sa, float* __restrict__ sb, float* __restrict__ btot)
{
    const int tid = threadIdx.x;
    #pragma unroll
    for (int p = 0; p < 2; p++) {
        int idx = tid + p * 256;          // 512 = NREL * F
        float mean = sums[idx] * (1.0f / NN);
        float var = sumsq[idx] * (1.0f / NN) - mean * mean;
        float g = gamma[idx] * rsqrtf(var + BN_EPS);
        sa[idx] = g;
        sb[idx] = beta[idx] - mean * g;
    }
    if (tid < F)
        btot[tid] = bself[tid] + b2[tid] + b2[F + tid] + b2[2 * F + tid] + b2[3 * F + tid];
}

// ------ GEMM1 (barrier-light): h1 = bf16(hbuf @ W1[r] + b1[r]) in-place, BN stats ------
// A and B fragments loaded directly global -> VGPR (16B contiguous chunks).
__global__ __launch_bounds__(256) void gemm1_kernel(
    ushort* __restrict__ hbuf, const ushort* __restrict__ Wt_g,
    const float* __restrict__ b1,
    float* __restrict__ sums, float* __restrict__ sumsq)
{
    __shared__ __attribute__((aligned(16))) ushort At[ROWS * LDW];  // 17.4 KB
    __shared__ float csum[F], csq[F];

    const int tid = threadIdx.x;
    const int r = blockIdx.y;
    const int n0 = blockIdx.x * ROWS;
    const int lane = tid & 63, w = tid >> 6;
    const int m = lane & 15, quad = lane >> 4;
    const int rb = w * 16;

    if (tid < F) { csum[tid] = 0.f; csq[tid] = 0.f; }
    __syncthreads();

    // fragment base pointers (16B-aligned contiguous chunks)
    const ushort* Ap = hbuf + ((size_t)r * NN + n0 + rb + m) * F + quad * 8;
    const ushort* Bp = Wt_g + (size_t)r * F * F + m * F + quad * 8;

    floatx4 acc[8];
    #pragma unroll
    for (int g = 0; g < 8; g++) acc[g] = (floatx4)0.f;

    #pragma unroll
    for (int kk = 0; kk < 4; kk++) {
        short8 a = *(const short8*)(Ap + kk * 32);
        #pragma unroll
        for (int g = 0; g < 8; g++) {
            short8 b = *(const short8*)(Bp + g * 16 * F + kk * 32);
            acc[g] = __builtin_amdgcn_mfma_f32_16x16x32_bf16(a, b, acc[g], 0, 0, 0);
        }
    }

    // epilogue: bias, BN partials, bf16 into At (C layout: row=quad*4+i, col=g*16+m)
    #pragma unroll
    for (int g = 0; g < 8; g++) {
        int c = g * 16 + m;
        float bv = b1[r * F + c];
        float ls = 0.f, lq = 0.f;
        #pragma unroll
        for (int i = 0; i < 4; i++) {
            int lrow = rb + quad * 4 + i;
            float v = acc[g][i] + bv;
            At[lrow * LDW + c] = f2bf(v);
            if (n0 + lrow < NN) { ls += v; lq += v * v; }
        }
        atomicAdd(&csum[c], ls);
        atomicAdd(&csq[c], lq);
    }
    __syncthreads();

    // coalesced write-back in-place (block-exclusive rows)
    #pragma unroll
    for (int p = 0; p < 4; p++) {
        int cc = tid + p * 256;
        int row = cc >> 4, off = (cc & 15) * 8;
        if (n0 + row < NN)
            *(uint4*)(hbuf + ((size_t)r * NN + n0 + row) * F + off) =
                *(const uint4*)&At[row * LDW + off];
    }
    if (tid < F) {
        atomicAdd(&sums[r * F + tid], csum[tid]);
        atomicAdd(&sumsq[r * F + tid], csq[tid]);
    }
}

// ------- GEMM2 (no LDS, no barriers): out = xb@Wself + sum_r relu(bn(h1_r))@W2[r] + btot -------
__global__ __launch_bounds__(256) void gemm2_kernel(
    const ushort* __restrict__ xb, const ushort* __restrict__ h1,
    const ushort* __restrict__ Wt_g,
    const float* __restrict__ sa, const float* __restrict__ sb,
    const float* __restrict__ btot, float* __restrict__ out)
{
    const int tid = threadIdx.x;
    const int n0 = blockIdx.x * ROWS;
    const int lane = tid & 63, w = tid >> 6;
    const int m = lane & 15, quad = lane >> 4;
    const int rb = w * 16;
    const int koff = quad * 8;

    floatx4 acc[8];
    #pragma unroll
    for (int g = 0; g < 8; g++) acc[g] = (floatx4)0.f;

    #pragma unroll
    for (int rel = 0; rel < 5; rel++) {
        const int mat = (rel < 4) ? (NREL + rel) : 8;
        const ushort* Bp = Wt_g + (size_t)mat * F * F + m * F + koff;
        if (rel < 4) {
            const ushort* hp = h1 + ((size_t)rel * NN + n0 + rb + m) * F + koff;
            const float* sap = sa + rel * F + koff;
            const float* sbp = sb + rel * F + koff;
            #pragma unroll
            for (int kk = 0; kk < 4; kk++) {
                uint4 rv = *(const uint4*)(hp + kk * 32);
                float4 ca0 = *(const float4*)(sap + kk * 32);
                float4 ca1 = *(const float4*)(sap + kk * 32 + 4);
                float4 cb0 = *(const float4*)(sbp + kk * 32);
                float4 cb1 = *(const float4*)(sbp + kk * 32 + 4);
                union { uint4 u; short8 s; } av;
                av.u.x = pk2(fmaxf(fmaf(ubf(rv.x << 16),          ca0.x, cb0.x), 0.f),
                             fmaxf(fmaf(ubf(rv.x & 0xffff0000u),  ca0.y, cb0.y), 0.f));
                av.u.y = pk2(fmaxf(fmaf(ubf(rv.y << 16),          ca0.z, cb0.z), 0.f),
                             fmaxf(fmaf(ubf(rv.y & 0xffff0000u),  ca0.w, cb0.w), 0.f));
                av.u.z = pk2(fmaxf(fmaf(ubf(rv.z << 16),          ca1.x, cb1.x), 0.f),
                             fmaxf(fmaf(ubf(rv.z & 0xffff0000u),  ca1.y, cb1.y), 0.f));
                av.u.w = pk2(fmaxf(fmaf(ubf(rv.w << 16),          ca1.z, cb1.z), 0.f),
                             fmaxf(fmaf(ubf(rv.w & 0xffff0000u),  ca1.w, cb1.w), 0.f));
                #pragma unroll
                for (int g = 0; g < 8; g++) {
                    short8 b = *(const short8*)(Bp + g * 16 * F + kk * 32);
                    acc[g] = __builtin_amdgcn_mfma_f32_16x16x32_bf16(av.s, b, acc[g], 0, 0, 0);
                }
            }
        } else {
            const ushort* xp = xb + (size_t)(n0 + rb + m) * F + koff;
            #pragma unroll
            for (int kk = 0; kk < 4; kk++) {
                short8 a = *(const short8*)(xp + kk * 32);
                #pragma unroll
                for (int g = 0; g < 8; g++) {
                    short8 b = *(const short8*)(Bp + g * 16 * F + kk * 32);
                    acc[g] = __builtin_amdgcn_mfma_f32_16x16x32_bf16(a, b, acc[g], 0, 0, 0);
                }
            }
        }
    }

    // epilogue: direct C-layout f32 stores
    #pragma unroll
    for (int g = 0; g < 8; g++) {
        int c = g * 16 + m;
        float bv = btot[c];
        #pragma unroll
        for (int i = 0; i < 4; i++) {
            int n = n0 + rb + quad * 4 + i;
            if (n < NN) out[(size_t)n * F + c] = acc[g][i] + bv;
        }
    }
}

extern "C" void kernel_launch(void* const* d_in, const int* in_sizes, int n_in,
                              void* d_out, int out_size, void* d_ws, size_t ws_size,
                              hipStream_t stream) {
    const float* x     = (const float*)d_in[0];
    const int*   ei    = (const int*)d_in[1];
    const int*   et    = (const int*)d_in[2];
    const float* Wself = (const float*)d_in[3];
    const float* bself = (const float*)d_in[4];
    const float* W1    = (const float*)d_in[5];
    const float* b1    = (const float*)d_in[6];
    const float* gamma = (const float*)d_in[7];
    const float* beta  = (const float*)d_in[8];
    const float* W2    = (const float*)d_in[9];
    const float* b2    = (const float*)d_in[10];
    float* out = (float*)d_out;

    // workspace layout
    ushort* hbuf = (ushort*)d_ws;                       // [4, NN, 128] bf16: h_in -> h1 in-place
    ushort* xb   = hbuf + (size_t)RN * F;               // [NN, 128] bf16
    ushort* Wt_g = xb + (size_t)NN * F;                 // [9, 128, 128] bf16
    float*  sums  = (float*)(Wt_g + 9 * F * F);         // [4, 128]
    float*  sumsq = sums + NREL * F;                    // [4, 128]
    float*  sa    = sumsq + NREL * F;                   // [4, 128]
    float*  sb    = sa + NREL * F;                      // [4, 128]
    float*  btot  = sb + NREL * F;                      // [128]
    int* counts     = (int*)(btot + F);                 // [RN]
    int* rowptr     = counts + RN;                      // [RN+1]
    int* cursor     = rowptr + RN + 1;                  // [RN]
    int* sorted_src = cursor + RN;                      // [NE]
    int* bsum       = sorted_src + NE;                  // [256]
    int* boff       = bsum + 256;                       // [256]

    // zero: sums + sumsq + (sa,sb,btot harmless) + counts (contiguous)
    hipMemsetAsync(sums, 0, (4 * (size_t)NREL * F + F + RN) * sizeof(float), stream);

    prep_kernel<<<9, 256, 0, stream>>>(W1, W2, Wself, Wt_g);
    xb_kernel<<<NN * F / 1024, 256, 0, stream>>>(x, xb);
    hist_kernel<<<(NE + 255) / 256, 256, 0, stream>>>(ei, et, counts);
    scan1_kernel<<<NB, 256, 0, stream>>>(counts, rowptr, bsum);
    scan2_kernel<<<1, 256, 0, stream>>>(bsum, boff, rowptr);
    scan3_kernel<<<NB, 256, 0, stream>>>(rowptr, boff, cursor);
    reorder_kernel<<<(NE + 255) / 256, 256, 0, stream>>>(ei, et, cursor, sorted_src);
    gather_kernel<<<RN * 16 / 256, 256, 0, stream>>>(xb, rowptr, sorted_src, hbuf);
    {
        dim3 grid((NN + ROWS - 1) / ROWS, NREL);
        gemm1_kernel<<<grid, 256, 0, stream>>>(hbuf, Wt_g, b1, sums, sumsq);
    }
    bncoef_kernel<<<1, 256, 0, stream>>>(sums, sumsq, gamma, beta, b2, bself, sa, sb, btot);
    {
        int grid = (NN + ROWS - 1) / ROWS;
        gemm2_kernel<<<grid, 256, 0, stream>>>(xb, hbuf, Wt_g, sa, sb, btot, out);
    }
}

// Round 7
// 322.733 us; speedup vs baseline: 1.3556x; 1.3556x over previous
//
#include <hip/hip_runtime.h>

#define NN 50000
#define NE 800000
#define F 128
#define NREL 4
#define RN (NREL * NN)          // number of segments
#define NB 196                  // scan blocks: ceil(RN / 1024)
#define BN_EPS 1e-5f
#define TILE 128                // rows per block tile
#define NT1 391                 // ceil(NN / TILE)
#define LDW 136                 // padded LDS row stride in bf16 elems

typedef __attribute__((ext_vector_type(8))) short short8;
typedef __attribute__((ext_vector_type(4))) float floatx4;

__device__ __forceinline__ ushort f2bf(float f) {
    union { float f; unsigned u; } v; v.f = f;
    unsigned r = v.u + 0x7fffu + ((v.u >> 16) & 1u);
    return (ushort)(r >> 16);
}
__device__ __forceinline__ float bf2f(ushort h) {
    union { unsigned u; float f; } v; v.u = ((unsigned)h) << 16;
    return v.f;
}
__device__ __forceinline__ float ubf(unsigned bits) {
    union { unsigned u; float f; } v; v.u = bits; return v.f;
}
__device__ __forceinline__ unsigned pk2(float a, float b) {
    return (unsigned)f2bf(a) | ((unsigned)f2bf(b) << 16);
}
__device__ __forceinline__ void acc_u4(float* acc, uint4 v) {
    acc[0] += ubf(v.x << 16); acc[1] += ubf(v.x & 0xffff0000u);
    acc[2] += ubf(v.y << 16); acc[3] += ubf(v.y & 0xffff0000u);
    acc[4] += ubf(v.z << 16); acc[5] += ubf(v.z & 0xffff0000u);
    acc[6] += ubf(v.w << 16); acc[7] += ubf(v.w & 0xffff0000u);
}

// ---------------- xb = bf16(x) ----------------
__global__ __launch_bounds__(256) void xb_kernel(
    const float* __restrict__ x, ushort* __restrict__ xb)
{
    int i = blockIdx.x * 256 + threadIdx.x;   // 4 floats/thread; NN*F/4 threads exactly
    float4 v = *(const float4*)(x + (size_t)i * 4);
    uint2 u;
    u.x = pk2(v.x, v.y);
    u.y = pk2(v.z, v.w);
    *(uint2*)(xb + (size_t)i * 4) = u;
}

// ---------------- histogram ----------------
__global__ __launch_bounds__(256) void hist_kernel(
    const int* __restrict__ ei, const int* __restrict__ et, int* __restrict__ counts)
{
    int e = blockIdx.x * 256 + threadIdx.x;
    if (e >= NE) return;
    atomicAdd(&counts[et[e] * NN + ei[NE + e]], 1);
}

// ---------------- scan stage 1 ----------------
__global__ __launch_bounds__(256) void scan1_kernel(
    const int* __restrict__ counts, int* __restrict__ rowptr, int* __restrict__ bsum)
{
    __shared__ int wsum[4];
    const int tid = threadIdx.x;
    const int base = blockIdx.x * 1024 + tid * 4;
    int c[4];
    #pragma unroll
    for (int j = 0; j < 4; j++) c[j] = (base + j < RN) ? counts[base + j] : 0;
    int tsum = c[0] + c[1] + c[2] + c[3];
    const int lane = tid & 63, wv = tid >> 6;
    int s = tsum;
    #pragma unroll
    for (int d = 1; d < 64; d <<= 1) { int t = __shfl_up(s, d); if (lane >= d) s += t; }
    if (lane == 63) wsum[wv] = s;
    __syncthreads();
    int wave_off = 0;
    #pragma unroll
    for (int w = 0; w < 4; w++) if (w < wv) wave_off += wsum[w];
    int run = wave_off + s - tsum;
    #pragma unroll
    for (int j = 0; j < 4; j++) {
        if (base + j < RN) rowptr[base + j] = run;
        run += c[j];
    }
    if (tid == 0) bsum[blockIdx.x] = wsum[0] + wsum[1] + wsum[2] + wsum[3];
}

// ---------------- scan stage 2 ----------------
__global__ __launch_bounds__(256) void scan2_kernel(
    const int* __restrict__ bsum, int* __restrict__ boff, int* __restrict__ rowptr)
{
    __shared__ int wsum[4];
    const int tid = threadIdx.x;
    int v = (tid < NB) ? bsum[tid] : 0;
    const int lane = tid & 63, wv = tid >> 6;
    int s = v;
    #pragma unroll
    for (int d = 1; d < 64; d <<= 1) { int t = __shfl_up(s, d); if (lane >= d) s += t; }
    if (lane == 63) wsum[wv] = s;
    __syncthreads();
    int wave_off = 0;
    #pragma unroll
    for (int w = 0; w < 4; w++) if (w < wv) wave_off += wsum[w];
    if (tid < NB) boff[tid] = wave_off + s - v;
    if (tid == 0) rowptr[RN] = wsum[0] + wsum[1] + wsum[2] + wsum[3];
}

// ---------------- scan stage 3 ----------------
__global__ __launch_bounds__(256) void scan3_kernel(
    int* __restrict__ rowptr, const int* __restrict__ boff, int* __restrict__ cursor)
{
    const int base = blockIdx.x * 1024 + threadIdx.x * 4;
    const int off = boff[blockIdx.x];
    #pragma unroll
    for (int j = 0; j < 4; j++) {
        int idx = base + j;
        if (idx < RN) { int v = rowptr[idx] + off; rowptr[idx] = v; cursor[idx] = v; }
    }
}

// ---------------- reorder ----------------
__global__ __launch_bounds__(256) void reorder_kernel(
    const int* __restrict__ ei, const int* __restrict__ et,
    int* __restrict__ cursor, int* __restrict__ sorted_src)
{
    int e = blockIdx.x * 256 + threadIdx.x;
    if (e >= NE) return;
    int key = et[e] * NN + ei[NE + e];
    int pos = atomicAdd(&cursor[key], 1);
    sorted_src[pos] = ei[e];
}

// ------- gather: hbuf[row] = bf16(xb[n] + sum_{e in seg(row)} xb[src_e]) -------
__global__ __launch_bounds__(256) void gather_kernel(
    const ushort* __restrict__ xb, const int* __restrict__ rowptr,
    const int* __restrict__ sorted_src, ushort* __restrict__ hbuf)
{
    const int t = blockIdx.x * 256 + threadIdx.x;
    const int row = t >> 4;               // segment id in [0, RN)
    const int lane = t & 15;              // 16 lanes x 8 bf16 = 128 feats
    const int n = row % NN;               // dst node

    const uint4* xv = (const uint4*)xb;   // row stride = 16 uint4
    float acc[8];
    {
        uint4 v = xv[n * 16 + lane];
        acc[0] = ubf(v.x << 16); acc[1] = ubf(v.x & 0xffff0000u);
        acc[2] = ubf(v.y << 16); acc[3] = ubf(v.y & 0xffff0000u);
        acc[4] = ubf(v.z << 16); acc[5] = ubf(v.z & 0xffff0000u);
        acc[6] = ubf(v.w << 16); acc[7] = ubf(v.w & 0xffff0000u);
    }
    int e = rowptr[row];
    const int e1 = rowptr[row + 1];
    for (; e + 4 <= e1; e += 4) {
        int s0 = sorted_src[e], s1 = sorted_src[e + 1];
        int s2 = sorted_src[e + 2], s3 = sorted_src[e + 3];
        uint4 a = xv[s0 * 16 + lane];
        uint4 b = xv[s1 * 16 + lane];
        uint4 c = xv[s2 * 16 + lane];
        uint4 d = xv[s3 * 16 + lane];
        acc_u4(acc, a); acc_u4(acc, b); acc_u4(acc, c); acc_u4(acc, d);
    }
    for (; e < e1; ++e) {
        int s0 = sorted_src[e];
        acc_u4(acc, xv[s0 * 16 + lane]);
    }
    uint4 o;
    o.x = pk2(acc[0], acc[1]);
    o.y = pk2(acc[2], acc[3]);
    o.z = pk2(acc[4], acc[5]);
    o.w = pk2(acc[6], acc[7]);
    *(uint4*)(hbuf + (size_t)row * F + lane * 8) = o;
}

// ---------------- prep: weights -> bf16 transposed Wt_g[mat][n][k] ----------------
__global__ __launch_bounds__(256) void prep_kernel(
    const float* __restrict__ W1, const float* __restrict__ W2,
    const float* __restrict__ Wself, ushort* __restrict__ Wt_g)
{
    __shared__ ushort Lt[F * F];
    int m = blockIdx.x;
    const float* src = (m < 4) ? (W1 + (size_t)m * F * F)
                     : (m < 8) ? (W2 + (size_t)(m - 4) * F * F)
                               : Wself;
    int tid = threadIdx.x;
    #pragma unroll
    for (int p = 0; p < 16; p++) {
        int i4 = tid + p * 256;
        int k = i4 >> 5;
        int n4 = (i4 & 31) * 4;
        float4 v = *(const float4*)(src + (size_t)k * F + n4);
        Lt[(n4 + 0) * F + k] = f2bf(v.x);
        Lt[(n4 + 1) * F + k] = f2bf(v.y);
        Lt[(n4 + 2) * F + k] = f2bf(v.z);
        Lt[(n4 + 3) * F + k] = f2bf(v.w);
    }
    __syncthreads();
    #pragma unroll
    for (int p = 0; p < 8; p++) {
        int c = tid + p * 256;
        *(uint4*)(Wt_g + (size_t)m * F * F + c * 8) = *(const uint4*)&Lt[c * 8];
    }
}

// ------ GEMM1: h1 = bf16(hbuf @ W1[r] + b1[r]) in-place; per-block BN partials ------
__global__ __launch_bounds__(256, 2) void gemm1_kernel(
    ushort* __restrict__ hbuf, const ushort* __restrict__ Wt_g,
    const float* __restrict__ b1, float* __restrict__ partials)
{
    __shared__ __attribute__((aligned(16))) ushort Sh[2 * TILE * LDW];  // At | Wt, 69.6 KB
    __shared__ float csum[F], csq[F];
    ushort* At = Sh;
    ushort* Wt = Sh + TILE * LDW;

    const int tid = threadIdx.x;
    const int r = blockIdx.y;
    const int n0 = blockIdx.x * TILE;

    if (tid < F) { csum[tid] = 0.f; csq[tid] = 0.f; }

    // stage A (128 rows x 16 chunks of 8 ushorts = 2048 chunks)
    #pragma unroll
    for (int p = 0; p < 8; p++) {
        int c = tid + p * 256;
        int row = c >> 4, off = (c & 15) * 8;
        uint4 v = make_uint4(0u, 0u, 0u, 0u);
        if (n0 + row < NN)
            v = *(const uint4*)(hbuf + ((size_t)r * NN + n0 + row) * F + off);
        *(uint4*)&At[row * LDW + off] = v;
    }
    // stage Wt
    {
        const ushort* wg = Wt_g + (size_t)r * F * F;
        #pragma unroll
        for (int p = 0; p < 8; p++) {
            int c = tid + p * 256;
            int n = c >> 4, off = (c & 15) * 8;
            *(uint4*)&Wt[n * LDW + off] = *(const uint4*)(wg + c * 8);
        }
    }
    __syncthreads();

    const int lane = tid & 63, w = tid >> 6;
    const int m = lane & 15, quad = lane >> 4;
    floatx4 acc[2][8];
    #pragma unroll
    for (int rg = 0; rg < 2; rg++)
        #pragma unroll
        for (int g = 0; g < 8; g++) acc[rg][g] = (floatx4)0.f;

    const ushort* Ap0 = &At[(w * 32 + m) * LDW + quad * 8];
    const ushort* Ap1 = Ap0 + 16 * LDW;
    const ushort* Bp  = &Wt[m * LDW + quad * 8];
    #pragma unroll
    for (int kk = 0; kk < 4; kk++) {
        short8 a0 = *(const short8*)(Ap0 + kk * 32);
        short8 a1 = *(const short8*)(Ap1 + kk * 32);
        #pragma unroll
        for (int g = 0; g < 8; g++) {
            short8 b = *(const short8*)(Bp + g * 16 * LDW + kk * 32);
            acc[0][g] = __builtin_amdgcn_mfma_f32_16x16x32_bf16(a0, b, acc[0][g], 0, 0, 0);
            acc[1][g] = __builtin_amdgcn_mfma_f32_16x16x32_bf16(a1, b, acc[1][g], 0, 0, 0);
        }
    }
    __syncthreads();   // all waves done reading At/Wt

    // epilogue: bias, bf16 into At, shuffle-reduced BN partials into LDS
    #pragma unroll
    for (int rg = 0; rg < 2; rg++) {
        const int rb = w * 32 + rg * 16;
        #pragma unroll
        for (int g = 0; g < 8; g++) {
            int c = g * 16 + m;
            float bv = b1[r * F + c];
            float ls = 0.f, lq = 0.f;
            #pragma unroll
            for (int i = 0; i < 4; i++) {
                int lrow = rb + quad * 4 + i;
                float v = acc[rg][g][i] + bv;
                At[lrow * LDW + c] = f2bf(v);
                if (n0 + lrow < NN) { ls += v; lq += v * v; }
            }
            ls += __shfl_xor(ls, 16); ls += __shfl_xor(ls, 32);
            lq += __shfl_xor(lq, 16); lq += __shfl_xor(lq, 32);
            if (quad == 0) { atomicAdd(&csum[c], ls); atomicAdd(&csq[c], lq); }
        }
    }
    __syncthreads();

    // write-back in-place (block-exclusive rows) + one coalesced partial row
    #pragma unroll
    for (int p = 0; p < 8; p++) {
        int cc = tid + p * 256;
        int row = cc >> 4, off = (cc & 15) * 8;
        if (n0 + row < NN)
            *(uint4*)(hbuf + ((size_t)r * NN + n0 + row) * F + off) =
                *(const uint4*)&At[row * LDW + off];
    }
    partials[((size_t)r * NT1 + blockIdx.x) * 256 + tid] =
        (tid < F) ? csum[tid] : csq[tid - F];
}

// ---------------- bncoef: reduce partials -> sa/sb; btot ----------------
__global__ __launch_bounds__(256) void bncoef_kernel(
    const float* __restrict__ partials,
    const float* __restrict__ gamma, const float* __restrict__ beta,
    const float* __restrict__ b2, const float* __restrict__ bself,
    float* __restrict__ sa, float* __restrict__ sb, float* __restrict__ btot)
{
    const int id = blockIdx.x * 256 + threadIdx.x;   // 0..511
    const int rel = id >> 7, col = id & 127;
    float s = 0.f, q = 0.f;
    const float* p = partials + (size_t)rel * NT1 * 256;
    for (int b = 0; b < NT1; b++) {
        s += p[b * 256 + col];
        q += p[b * 256 + 128 + col];
    }
    float mean = s * (1.0f / NN);
    float var = q * (1.0f / NN) - mean * mean;
    float g = gamma[id] * rsqrtf(var + BN_EPS);
    sa[id] = g;
    sb[id] = beta[id] - mean * g;
    if (blockIdx.x == 0 && threadIdx.x < F) {
        int c = threadIdx.x;
        btot[c] = bself[c] + b2[c] + b2[F + c] + b2[2 * F + c] + b2[3 * F + c];
    }
}

// ------- GEMM2: out = xb@Wself + sum_r relu(bn(h1_r))@W2[r] + btot -------
__global__ __launch_bounds__(256, 2) void gemm2_kernel(
    const ushort* __restrict__ xb, const ushort* __restrict__ h1,
    const ushort* __restrict__ Wt_g,
    const float* __restrict__ sa, const float* __restrict__ sb,
    const float* __restrict__ btot, float* __restrict__ out)
{
    __shared__ __attribute__((aligned(16))) ushort Sh[2 * TILE * LDW];  // At | Wt; Ct reuse
    __shared__ float sAl[NREL * F], sBl[NREL * F];
    ushort* At = Sh;
    ushort* Wt = Sh + TILE * LDW;

    const int tid = threadIdx.x;
    const int n0 = blockIdx.x * TILE;

    #pragma unroll
    for (int p = 0; p < 2; p++) {
        int idx = tid + p * 256;
        sAl[idx] = sa[idx];
        sBl[idx] = sb[idx];
    }

    const int lane = tid & 63, w = tid >> 6;
    const int m = lane & 15, quad = lane >> 4;
    floatx4 acc[2][8];
    #pragma unroll
    for (int rg = 0; rg < 2; rg++)
        #pragma unroll
        for (int g = 0; g < 8; g++) acc[rg][g] = (floatx4)0.f;

    for (int rel = 0; rel < 5; rel++) {
        __syncthreads();   // prior readers done (and sAl/sBl ready on first iter)
        if (rel < 4) {
            // stage A = bf16(relu(bn(h1))) : 2048 chunks
            #pragma unroll
            for (int p = 0; p < 8; p++) {
                int c = tid + p * 256;
                int row = c >> 4, off = (c & 15) * 8;
                unsigned uu[4] = {0, 0, 0, 0};
                if (n0 + row < NN) {
                    uint4 v = *(const uint4*)(h1 + ((size_t)rel * NN + n0 + row) * F + off);
                    uu[0] = v.x; uu[1] = v.y; uu[2] = v.z; uu[3] = v.w;
                    #pragma unroll
                    for (int j = 0; j < 4; j++) {
                        int c0 = off + j * 2;
                        float v0 = bf2f((ushort)(uu[j] & 0xffffu));
                        float v1 = bf2f((ushort)(uu[j] >> 16));
                        v0 = fmaxf(fmaf(v0, sAl[rel * F + c0], sBl[rel * F + c0]), 0.f);
                        v1 = fmaxf(fmaf(v1, sAl[rel * F + c0 + 1], sBl[rel * F + c0 + 1]), 0.f);
                        uu[j] = pk2(v0, v1);
                    }
                }
                *(uint4*)&At[row * LDW + off] = make_uint4(uu[0], uu[1], uu[2], uu[3]);
            }
        } else {
            // stage A = xb (already bf16)
            #pragma unroll
            for (int p = 0; p < 8; p++) {
                int c = tid + p * 256;
                int row = c >> 4, off = (c & 15) * 8;
                uint4 v = make_uint4(0u, 0u, 0u, 0u);
                if (n0 + row < NN)
                    v = *(const uint4*)(xb + (size_t)(n0 + row) * F + off);
                *(uint4*)&At[row * LDW + off] = v;
            }
        }
        // stage Wt
        {
            int mat = (rel < 4) ? (NREL + rel) : 8;
            const ushort* wg = Wt_g + (size_t)mat * F * F;
            #pragma unroll
            for (int p = 0; p < 8; p++) {
                int c = tid + p * 256;
                int n = c >> 4, off = (c & 15) * 8;
                *(uint4*)&Wt[n * LDW + off] = *(const uint4*)(wg + c * 8);
            }
        }
        __syncthreads();
        const ushort* Ap0 = &At[(w * 32 + m) * LDW + quad * 8];
        const ushort* Ap1 = Ap0 + 16 * LDW;
        const ushort* Bp  = &Wt[m * LDW + quad * 8];
        #pragma unroll
        for (int kk = 0; kk < 4; kk++) {
            short8 a0 = *(const short8*)(Ap0 + kk * 32);
            short8 a1 = *(const short8*)(Ap1 + kk * 32);
            #pragma unroll
            for (int g = 0; g < 8; g++) {
                short8 b = *(const short8*)(Bp + g * 16 * LDW + kk * 32);
                acc[0][g] = __builtin_amdgcn_mfma_f32_16x16x32_bf16(a0, b, acc[0][g], 0, 0, 0);
                acc[1][g] = __builtin_amdgcn_mfma_f32_16x16x32_bf16(a1, b, acc[1][g], 0, 0, 0);
            }
        }
    }
    __syncthreads();   // all readers done; Sh becomes f32 Ct (128x128 = 64 KB <= 69.6 KB)

    float* Ct = (float*)Sh;
    #pragma unroll
    for (int rg = 0; rg < 2; rg++) {
        const int rb = w * 32 + rg * 16;
        #pragma unroll
        for (int g = 0; g < 8; g++) {
            int c = g * 16 + m;
            float bv = btot[c];
            #pragma unroll
            for (int i = 0; i < 4; i++) {
                int lrow = rb + quad * 4 + i;
                Ct[lrow * F + c] = acc[rg][g][i] + bv;
            }
        }
    }
    __syncthreads();
    #pragma unroll
    for (int p = 0; p < 16; p++) {
        int i4 = tid + p * 256;              // 4096 float4: 128 rows x 32
        int row = i4 >> 5;
        int c4 = (i4 & 31) * 4;
        if (n0 + row < NN)
            *(float4*)(out + (size_t)(n0 + row) * F + c4) = *(const float4*)&Ct[row * F + c4];
    }
}

extern "C" void kernel_launch(void* const* d_in, const int* in_sizes, int n_in,
                              void* d_out, int out_size, void* d_ws, size_t ws_size,
                              hipStream_t stream) {
    const float* x     = (const float*)d_in[0];
    const int*   ei    = (const int*)d_in[1];
    const int*   et    = (const int*)d_in[2];
    const float* Wself = (const float*)d_in[3];
    const float* bself = (const float*)d_in[4];
    const float* W1    = (const float*)d_in[5];
    const float* b1    = (const float*)d_in[6];
    const float* gamma = (const float*)d_in[7];
    const float* beta  = (const float*)d_in[8];
    const float* W2    = (const float*)d_in[9];
    const float* b2    = (const float*)d_in[10];
    float* out = (float*)d_out;

    // workspace layout
    ushort* hbuf = (ushort*)d_ws;                       // [4, NN, 128] bf16: h_in -> h1 in-place
    ushort* xb   = hbuf + (size_t)RN * F;               // [NN, 128] bf16
    ushort* Wt_g = xb + (size_t)NN * F;                 // [9, 128, 128] bf16
    float*  partials = (float*)(Wt_g + 9 * F * F);      // [4, NT1, 256]
    float*  sa    = partials + (size_t)NREL * NT1 * 256;// [4, 128]
    float*  sb    = sa + NREL * F;                      // [4, 128]
    float*  btot  = sb + NREL * F;                      // [128]
    int* counts     = (int*)(btot + F);                 // [RN]
    int* rowptr     = counts + RN;                      // [RN+1]
    int* cursor     = rowptr + RN + 1;                  // [RN]
    int* sorted_src = cursor + RN;                      // [NE]
    int* bsum       = sorted_src + NE;                  // [256]
    int* boff       = bsum + 256;                       // [256]

    hipMemsetAsync(counts, 0, (size_t)RN * sizeof(int), stream);

    prep_kernel<<<9, 256, 0, stream>>>(W1, W2, Wself, Wt_g);
    xb_kernel<<<NN * F / 1024, 256, 0, stream>>>(x, xb);
    hist_kernel<<<(NE + 255) / 256, 256, 0, stream>>>(ei, et, counts);
    scan1_kernel<<<NB, 256, 0, stream>>>(counts, rowptr, bsum);
    scan2_kernel<<<1, 256, 0, stream>>>(bsum, boff, rowptr);
    scan3_kernel<<<NB, 256, 0, stream>>>(rowptr, boff, cursor);
    reorder_kernel<<<(NE + 255) / 256, 256, 0, stream>>>(ei, et, cursor, sorted_src);
    gather_kernel<<<RN * 16 / 256, 256, 0, stream>>>(xb, rowptr, sorted_src, hbuf);
    {
        dim3 grid(NT1, NREL);
        gemm1_kernel<<<grid, 256, 0, stream>>>(hbuf, Wt_g, b1, partials);
    }
    bncoef_kernel<<<2, 256, 0, stream>>>(partials, gamma, beta, b2, bself, sa, sb, btot);
    gemm2_kernel<<<NT1, 256, 0, stream>>>(xb, hbuf, Wt_g, sa, sb, btot, out);
}